// Round 5
// baseline (1128.170 us; speedup 1.0000x reference)
//
#include <hip/hip_runtime.h>
#include <cstdint>
#include <cstddef>

#define EMB   256
#define NA    16384
#define NOBJ  32768
#define E1CNT 131072
#define E2CNT 262144
#define NDEC  1056
#define NDECP 1152
#define DEC_OFF ((size_t)NA * NDEC)
#define GRID  512

typedef unsigned short u16;
typedef __attribute__((ext_vector_type(8))) short bf16x8;
typedef __attribute__((ext_vector_type(4))) float f32x4;

// ---------------------------------------------------------------------------
// helpers
// ---------------------------------------------------------------------------
__device__ __forceinline__ u16 f2bf(float f) {
  union { float f; unsigned u; } x; x.f = f;
  unsigned u = x.u + 0x7FFFu + ((x.u >> 16) & 1u);
  return (u16)(u >> 16);
}
__device__ __forceinline__ float bf2f(u16 h) {
  union { unsigned u; float f; } x; x.u = ((unsigned)h) << 16;
  return x.f;
}
__device__ __forceinline__ void gload_lds16(const void* g, void* l) {
  __builtin_amdgcn_global_load_lds(
      (const __attribute__((address_space(1))) unsigned int*)g,
      (__attribute__((address_space(3))) unsigned int*)l, 16, 0, 0);
}

struct Params {
  const float *obj_x, *obj_pos, *agent_pos;
  const int *agent_idx, *obj_idx, *src, *dst;
  const float *W1, *b1, *W2, *b2, *Wm, *bm, *Wu, *bu, *Wd, *bd;
  float* out;
  u16 *Aobj, *zobj, *s1, *ybuf, *xb, *agg, *w1t, *wdt, *c1t, *wuf;
  float *d1, *d2;
  int *bar, *cur1, *cur2, *rp1, *rp2, *so, *ss;
};

// device-scope monotonic grid barrier (bar zeroed by host memset each launch)
__device__ __forceinline__ void gridbar(int* bar, int ph) {
  __syncthreads();
  if (threadIdx.x == 0) {
    __threadfence();
    __hip_atomic_fetch_add(bar, 1, __ATOMIC_RELEASE, __HIP_MEMORY_SCOPE_AGENT);
    while (__hip_atomic_load(bar, __ATOMIC_ACQUIRE, __HIP_MEMORY_SCOPE_AGENT) < GRID * ph)
      __builtin_amdgcn_s_sleep(4);
    __threadfence();
  }
  __syncthreads();
}

// ---------------------------------------------------------------------------
// GEMM tile (m97-style): MODE 0 = +biasB -> bf16 | 1 = +deg*biasA+biasB -> bf16
//   2 = relu(+deg*biasA+biasB) -> bf16 | 3 = +biasB -> fp32 col-guarded
// ---------------------------------------------------------------------------
template<int BMT, int BNT, int WM, int WN, int MODE>
__device__ __forceinline__ void gemm_tile(
    u16* As, u16* Bs, int m0, int n0,
    const u16* A1, const u16* A2, int lda, int ksw,
    const u16* BT, int ktot,
    const float* biasA, const float* biasB, const int* rp,
    u16* out16, float* out32, int ldo, int nmax)
{
  constexpr int FI = BMT / (WM * 16);
  constexpr int FJ = BNT / (WN * 16);
  constexpr int RA = BMT * 4 / 256;
  constexpr int RB = BNT * 4 / 256;
  const int tid  = threadIdx.x;
  const int lane = tid & 63;
  const int wave = tid >> 6;
  const int wm = wave % WM, wn = wave / WM;

  f32x4 acc[FI][FJ];
#pragma unroll
  for (int i = 0; i < FI; ++i)
#pragma unroll
    for (int j = 0; j < FJ; ++j) {
      acc[i][j][0] = 0.f; acc[i][j][1] = 0.f; acc[i][j][2] = 0.f; acc[i][j][3] = 0.f;
    }

  const int nk = ktot / 32;
  for (int kc = 0; kc < nk; ++kc) {
    const u16* Ab; int kof;
    if (kc * 32 < ksw) { Ab = A1; kof = kc * 32; }
    else               { Ab = A2; kof = kc * 32 - ksw; }
    __syncthreads();
#pragma unroll
    for (int r = 0; r < RA; ++r) {
      const int u = r * 256 + tid;
      gload_lds16(Ab + (size_t)(m0 + (u >> 2)) * lda + kof + (u & 3) * 8,
                  As + (size_t)u * 8);
    }
#pragma unroll
    for (int r = 0; r < RB; ++r) {
      const int u = r * 256 + tid;
      gload_lds16(BT + (size_t)(n0 + (u >> 2)) * ktot + kc * 32 + (u & 3) * 8,
                  Bs + (size_t)u * 8);
    }
    __syncthreads();
    bf16x8 a[FI], b[FJ];
#pragma unroll
    for (int i = 0; i < FI; ++i)
      a[i] = *(const bf16x8*)&As[(wm * FI * 16 + 16 * i + (lane & 15)) * 32 + (lane >> 4) * 8];
#pragma unroll
    for (int j = 0; j < FJ; ++j)
      b[j] = *(const bf16x8*)&Bs[(wn * FJ * 16 + 16 * j + (lane & 15)) * 32 + (lane >> 4) * 8];
#pragma unroll
    for (int i = 0; i < FI; ++i)
#pragma unroll
      for (int j = 0; j < FJ; ++j)
        acc[i][j] = __builtin_amdgcn_mfma_f32_16x16x32_bf16(a[i], b[j], acc[i][j], 0, 0, 0);
  }

#pragma unroll
  for (int i = 0; i < FI; ++i) {
    const int rbase = m0 + wm * FI * 16 + 16 * i + (lane >> 4) * 4;
    float deg[4];
    if constexpr (MODE == 1 || MODE == 2) {
#pragma unroll
      for (int r = 0; r < 4; ++r)
        deg[r] = (float)(rp[rbase + r + 1] - rp[rbase + r]);
    }
#pragma unroll
    for (int j = 0; j < FJ; ++j) {
      const int c = n0 + wn * FJ * 16 + 16 * j + (lane & 15);
      float bb;
      if constexpr (MODE == 3) bb = (c < nmax) ? biasB[c] : 0.f;
      else bb = biasB[c];
      float ba = 0.f;
      if constexpr (MODE == 1 || MODE == 2) ba = biasA[c];
#pragma unroll
      for (int r = 0; r < 4; ++r) {
        float v = acc[i][j][r] + bb;
        if constexpr (MODE == 1 || MODE == 2) v += deg[r] * ba;
        if constexpr (MODE == 2) v = fmaxf(v, 0.f);
        if constexpr (MODE == 3) {
          if (c < nmax) out32[(size_t)(rbase + r) * ldo + c] = v;
        } else {
          out16[(size_t)(rbase + r) * ldo + c] = f2bf(v);
        }
      }
    }
  }
}

// ---------------------------------------------------------------------------
// the mega-kernel
// ---------------------------------------------------------------------------
__global__ __launch_bounds__(256, 2) void mega(Params p) {
  __shared__ u16 smem[8192];              // 16 KB: As[0:4096] Bs[4096:8192]
  u16* As = smem;
  u16* Bs = smem + 4096;
  const int bid = blockIdx.x;
  const int tid = threadIdx.x;
  const int lane = tid & 63;
  const int BIG = 1 << 30;

  // ---- P1: count edges + prep Aobj + cvt w1t/wdt/wuf_bot -------------------
  // virtual blocks: [0,1536) count, [1536,13824) prep, [13824,15328) cvt
  for (int v = bid; v < 15328; v += GRID) {
    if (v < 1536) {
      const int e = v * 256 + tid;
      if (e < E1CNT) atomicAdd(&p.cur1[p.agent_idx[e]], 1);
      else           atomicAdd(&p.cur2[p.dst[e - E1CNT]], 1);
    } else if (v < 13824) {
      const int g = (v - 1536) * 256 + tid;     // over NOBJ*96
      const int row = g / 96, c = g - row * 96;
      float val = 0.f;
      if (c < 64)      val = p.obj_x[(size_t)row * 64 + c];
      else if (c < 66) val = p.obj_pos[(size_t)row * 2 + (c - 64)];
      p.Aobj[g] = f2bf(val);
    } else {
      const int e = (v - 13824) * 256 + tid;    // over 385024
      if (e < 24576) {                          // W1 -> w1t [256][96]
        const int n = e / 96, k = e - n * 96;
        p.w1t[e] = f2bf(k < 66 ? p.W1[(size_t)k * 256 + n] : 0.f);
      } else if (e < 319488) {                  // Wd -> wdt [1152][256]
        const int l = e - 24576;
        const int n = l >> 8, k = l & 255;
        p.wdt[l] = f2bf(n < NDEC ? p.Wd[(size_t)k * NDEC + n] : 0.f);
      } else {                                  // Wu bottom -> wuf[n][256+k]
        const int l = e - 319488;
        const int n = l >> 8, k = l & 255;
        p.wuf[(size_t)n * 512 + 256 + k] = f2bf(p.Wu[(size_t)(256 + k) * 256 + n]);
      }
    }
  }
  gridbar(p.bar, 1);

  // ---- P2: scan (blocks 0,1) + weight fusion (blocks 2..511) ---------------
  if (bid < 2) {
    int* cnt = (bid == 0) ? p.cur1 : p.cur2;
    int* rp  = (bid == 0) ? p.rp1  : p.rp2;
    int* partial = (int*)As;
    const int base = tid * 64;
    int local[64];
    int s = 0;
#pragma unroll
    for (int i = 0; i < 64; ++i) { local[i] = s; s += cnt[base + i]; }
    partial[tid] = s;
    __syncthreads();
    for (int off = 1; off < 256; off <<= 1) {
      int vv = (tid >= off) ? partial[tid - off] : 0;
      __syncthreads();
      partial[tid] += vv;
      __syncthreads();
    }
    const int offset = (tid == 0) ? 0 : partial[tid - 1];
#pragma unroll
    for (int i = 0; i < 64; ++i) {
      int vv = offset + local[i];
      rp[base + i]  = vv;
      cnt[base + i] = vv;
    }
    if (tid == 255) rp[NA] = partial[255];
  } else {
    // rows 0..255: C1T=(W2@Wm_top)^T ; 256..511: C2T into wuf top ; 512: d1 ; 513: d2
    for (int r = bid - 2; r < 514; r += (GRID - 2)) {
      if (r < 256) {
        const float* w2row = p.W2 + (size_t)tid * 256;
        float acc = 0.f;
        for (int j = 0; j < 256; ++j) acc += w2row[j] * p.Wm[(size_t)j * 256 + r];
        p.c1t[(size_t)r * 256 + tid] = f2bf(acc);
      } else if (r < 512) {
        const int n = r - 256;
        const float* w2row = p.W2 + (size_t)tid * 256;
        float acc = 0.f;
        for (int j = 0; j < 256; ++j) acc += w2row[j] * p.Wu[(size_t)j * 256 + n];
        p.wuf[(size_t)n * 512 + tid] = f2bf(acc);
      } else if (r == 512) {
        float acc = 0.f;
        for (int j = 0; j < 256; ++j) acc += p.b2[j] * p.Wm[(size_t)j * 256 + tid];
        p.d1[tid] = acc;
      } else {
        float acc = 0.f;
        for (int j = 0; j < 256; ++j) acc += p.b2[j] * p.Wu[(size_t)j * 256 + tid];
        p.d2[tid] = acc;
      }
    }
  }
  gridbar(p.bar, 2);

  // ---- P3: fill CSR --------------------------------------------------------
  for (int v = bid; v < 1536; v += GRID) {
    const int e = v * 256 + tid;
    if (e < E1CNT) {
      int pos = atomicAdd(&p.cur1[p.agent_idx[e]], 1);
      p.so[pos] = p.obj_idx[e];
    } else {
      const int i = e - E1CNT;
      int pos = atomicAdd(&p.cur2[p.dst[i]], 1);
      p.ss[pos] = p.src[i];
    }
  }
  gridbar(p.bar, 3);

  // ---- P4: zobj = Aobj @ w1t^T + b1  (512 tiles of 128x128) ----------------
  {
    const int m0 = (bid >> 1) * 128, n0 = (bid & 1) * 128;
    gemm_tile<128, 128, 2, 2, 0>(As, Bs, m0, n0, p.Aobj, p.Aobj, 96, BIG,
                                 p.w1t, 96, nullptr, p.b1, nullptr,
                                 p.zobj, nullptr, 256, 256);
  }
  gridbar(p.bar, 4);

  // ---- P5: reduce1 -> s1 (4-way edge unroll, wave per agent) ---------------
  {
    const int gw = bid * 4 + (tid >> 6);
    const float4 w0 = *(const float4*)(p.W1 + (size_t)64 * 256 + lane * 4);
    const float4 w1 = *(const float4*)(p.W1 + (size_t)65 * 256 + lane * 4);
    for (int a = gw; a < NA; a += GRID * 4) {
      const float ax = p.agent_pos[(size_t)a * 2], ay = p.agent_pos[(size_t)a * 2 + 1];
      const float t0 = ax * w0.x + ay * w1.x, t1 = ax * w0.y + ay * w1.y;
      const float t2 = ax * w0.z + ay * w1.z, t3 = ax * w0.w + ay * w1.w;
      float s0 = 0.f, s1v = 0.f, s2 = 0.f, s3 = 0.f;
      float u0 = 0.f, u1 = 0.f, u2 = 0.f, u3 = 0.f;
      const int e0 = p.rp1[a], e1 = p.rp1[a + 1];
      int i = e0;
      for (; i + 3 < e1; i += 4) {
        const int o0 = p.so[i], o1 = p.so[i + 1], o2 = p.so[i + 2], o3 = p.so[i + 3];
        const ushort4 z0 = *(const ushort4*)(p.zobj + (size_t)o0 * 256 + lane * 4);
        const ushort4 z1 = *(const ushort4*)(p.zobj + (size_t)o1 * 256 + lane * 4);
        const ushort4 z2 = *(const ushort4*)(p.zobj + (size_t)o2 * 256 + lane * 4);
        const ushort4 z3 = *(const ushort4*)(p.zobj + (size_t)o3 * 256 + lane * 4);
        s0 += fmaxf(bf2f(z0.x) - t0, 0.f) + fmaxf(bf2f(z1.x) - t0, 0.f);
        s1v += fmaxf(bf2f(z0.y) - t1, 0.f) + fmaxf(bf2f(z1.y) - t1, 0.f);
        s2 += fmaxf(bf2f(z0.z) - t2, 0.f) + fmaxf(bf2f(z1.z) - t2, 0.f);
        s3 += fmaxf(bf2f(z0.w) - t3, 0.f) + fmaxf(bf2f(z1.w) - t3, 0.f);
        u0 += fmaxf(bf2f(z2.x) - t0, 0.f) + fmaxf(bf2f(z3.x) - t0, 0.f);
        u1 += fmaxf(bf2f(z2.y) - t1, 0.f) + fmaxf(bf2f(z3.y) - t1, 0.f);
        u2 += fmaxf(bf2f(z2.z) - t2, 0.f) + fmaxf(bf2f(z3.z) - t2, 0.f);
        u3 += fmaxf(bf2f(z2.w) - t3, 0.f) + fmaxf(bf2f(z3.w) - t3, 0.f);
      }
      for (; i < e1; ++i) {
        const int o = p.so[i];
        const ushort4 z = *(const ushort4*)(p.zobj + (size_t)o * 256 + lane * 4);
        s0 += fmaxf(bf2f(z.x) - t0, 0.f);
        s1v += fmaxf(bf2f(z.y) - t1, 0.f);
        s2 += fmaxf(bf2f(z.z) - t2, 0.f);
        s3 += fmaxf(bf2f(z.w) - t3, 0.f);
      }
      ushort4 o4;
      o4.x = f2bf(s0 + u0); o4.y = f2bf(s1v + u1);
      o4.z = f2bf(s2 + u2); o4.w = f2bf(s3 + u3);
      *(ushort4*)(p.s1 + (size_t)a * 256 + lane * 4) = o4;
    }
  }
  gridbar(p.bar, 5);

  // ---- P6: y = s1 @ c1t^T + deg1*d1 + bm  (512 tiles of 64x128) ------------
  {
    const int m0 = (bid >> 1) * 64, n0 = (bid & 1) * 128;
    gemm_tile<64, 128, 1, 4, 1>(As, Bs, m0, n0, p.s1, p.s1, 256, BIG,
                                p.c1t, 256, p.d1, p.bm, p.rp1,
                                p.ybuf, nullptr, 256, 256);
  }
  gridbar(p.bar, 6);

  // ---- P7: reduce2 -> agg --------------------------------------------------
  {
    const int gw = bid * 4 + (tid >> 6);
    const float4 w0 = *(const float4*)(p.Wm + (size_t)256 * 256 + lane * 4);
    const float4 w1 = *(const float4*)(p.Wm + (size_t)257 * 256 + lane * 4);
    for (int d = gw; d < NA; d += GRID * 4) {
      const float dx = p.agent_pos[(size_t)d * 2], dy = p.agent_pos[(size_t)d * 2 + 1];
      float s0 = 0.f, s1v = 0.f, s2 = 0.f, s3 = 0.f;
      float u0 = 0.f, u1 = 0.f, u2 = 0.f, u3 = 0.f;
      const int e0 = p.rp2[d], e1 = p.rp2[d + 1];
      int i = e0;
      for (; i + 3 < e1; i += 4) {
        const int a0 = p.ss[i], a1 = p.ss[i + 1], a2 = p.ss[i + 2], a3 = p.ss[i + 3];
        const float rx0 = p.agent_pos[(size_t)a0 * 2] - dx, ry0 = p.agent_pos[(size_t)a0 * 2 + 1] - dy;
        const float rx1 = p.agent_pos[(size_t)a1 * 2] - dx, ry1 = p.agent_pos[(size_t)a1 * 2 + 1] - dy;
        const float rx2 = p.agent_pos[(size_t)a2 * 2] - dx, ry2 = p.agent_pos[(size_t)a2 * 2 + 1] - dy;
        const float rx3 = p.agent_pos[(size_t)a3 * 2] - dx, ry3 = p.agent_pos[(size_t)a3 * 2 + 1] - dy;
        const ushort4 v0 = *(const ushort4*)(p.ybuf + (size_t)a0 * 256 + lane * 4);
        const ushort4 v1 = *(const ushort4*)(p.ybuf + (size_t)a1 * 256 + lane * 4);
        const ushort4 v2 = *(const ushort4*)(p.ybuf + (size_t)a2 * 256 + lane * 4);
        const ushort4 v3 = *(const ushort4*)(p.ybuf + (size_t)a3 * 256 + lane * 4);
        s0 += fmaxf(bf2f(v0.x) + rx0 * w0.x + ry0 * w1.x, 0.f) + fmaxf(bf2f(v1.x) + rx1 * w0.x + ry1 * w1.x, 0.f);
        s1v += fmaxf(bf2f(v0.y) + rx0 * w0.y + ry0 * w1.y, 0.f) + fmaxf(bf2f(v1.y) + rx1 * w0.y + ry1 * w1.y, 0.f);
        s2 += fmaxf(bf2f(v0.z) + rx0 * w0.z + ry0 * w1.z, 0.f) + fmaxf(bf2f(v1.z) + rx1 * w0.z + ry1 * w1.z, 0.f);
        s3 += fmaxf(bf2f(v0.w) + rx0 * w0.w + ry0 * w1.w, 0.f) + fmaxf(bf2f(v1.w) + rx1 * w0.w + ry1 * w1.w, 0.f);
        u0 += fmaxf(bf2f(v2.x) + rx2 * w0.x + ry2 * w1.x, 0.f) + fmaxf(bf2f(v3.x) + rx3 * w0.x + ry3 * w1.x, 0.f);
        u1 += fmaxf(bf2f(v2.y) + rx2 * w0.y + ry2 * w1.y, 0.f) + fmaxf(bf2f(v3.y) + rx3 * w0.y + ry3 * w1.y, 0.f);
        u2 += fmaxf(bf2f(v2.z) + rx2 * w0.z + ry2 * w1.z, 0.f) + fmaxf(bf2f(v3.z) + rx3 * w0.z + ry3 * w1.z, 0.f);
        u3 += fmaxf(bf2f(v2.w) + rx2 * w0.w + ry2 * w1.w, 0.f) + fmaxf(bf2f(v3.w) + rx3 * w0.w + ry3 * w1.w, 0.f);
      }
      for (; i < e1; ++i) {
        const int a0 = p.ss[i];
        const float rx = p.agent_pos[(size_t)a0 * 2] - dx, ry = p.agent_pos[(size_t)a0 * 2 + 1] - dy;
        const ushort4 v0 = *(const ushort4*)(p.ybuf + (size_t)a0 * 256 + lane * 4);
        s0 += fmaxf(bf2f(v0.x) + rx * w0.x + ry * w1.x, 0.f);
        s1v += fmaxf(bf2f(v0.y) + rx * w0.y + ry * w1.y, 0.f);
        s2 += fmaxf(bf2f(v0.z) + rx * w0.z + ry * w1.z, 0.f);
        s3 += fmaxf(bf2f(v0.w) + rx * w0.w + ry * w1.w, 0.f);
      }
      ushort4 o4;
      o4.x = f2bf(s0 + u0); o4.y = f2bf(s1v + u1);
      o4.z = f2bf(s2 + u2); o4.w = f2bf(s3 + u3);
      *(ushort4*)(p.agg + (size_t)d * 256 + lane * 4) = o4;
    }
  }
  gridbar(p.bar, 7);

  // ---- P8: x = relu(s1@C2 + agg@Wu_bot + deg1*d2 + bu)  (512 tiles 64x128) -
  {
    const int m0 = (bid >> 1) * 64, n0 = (bid & 1) * 128;
    gemm_tile<64, 128, 1, 4, 2>(As, Bs, m0, n0, p.s1, p.agg, 256, 256,
                                p.wuf, 512, p.d2, p.bu, p.rp1,
                                p.xb, nullptr, 256, 256);
  }
  gridbar(p.bar, 8);

  // ---- P9: decoded = xb @ wdt^T + bd (1152 tiles 128x128) + batch ----------
  for (int t = bid; t < 1152; t += GRID) {
    const int m0 = (t / 9) * 128, n0 = (t % 9) * 128;
    gemm_tile<128, 128, 2, 2, 3>(As, Bs, m0, n0, p.xb, p.xb, 256, BIG,
                                 p.wdt, 256, nullptr, p.bd, nullptr,
                                 nullptr, p.out, NDEC, NDEC);
    if (n0 == 0) {
#pragma unroll
      for (int q = 0; q < 8; ++q) {
        const int idx = tid * 8 + q;
        p.out[DEC_OFF + (size_t)m0 * 16 + idx] = (float)(m0 + (idx >> 4));
      }
    }
  }
}

// ---------------------------------------------------------------------------
extern "C" void kernel_launch(void* const* d_in, const int* in_sizes, int n_in,
                              void* d_out, int out_size, void* d_ws, size_t ws_size,
                              hipStream_t stream) {
  Params p;
  p.obj_x     = (const float*)d_in[0];
  p.obj_pos   = (const float*)d_in[1];
  p.agent_pos = (const float*)d_in[2];
  const int* oae = (const int*)d_in[3];
  const int* ae  = (const int*)d_in[4];
  p.agent_idx = oae;
  p.obj_idx   = oae + E1CNT;
  p.src       = ae;
  p.dst       = ae + E2CNT;
  p.W1 = (const float*)d_in[5];  p.b1 = (const float*)d_in[6];
  p.W2 = (const float*)d_in[7];  p.b2 = (const float*)d_in[8];
  p.Wm = (const float*)d_in[9];  p.bm = (const float*)d_in[10];
  p.Wu = (const float*)d_in[11]; p.bu = (const float*)d_in[12];
  p.Wd = (const float*)d_in[13]; p.bd = (const float*)d_in[14];
  p.out = (float*)d_out;

  char* q = (char*)d_ws;
  p.Aobj = (u16*)q; q += (size_t)NOBJ * 96 * 2;          // 6.29 MB
  u16* zr = (u16*)q; q += (size_t)NOBJ * 256 * 2;        // 16.78 MB (zobj -> ybuf|xb)
  p.zobj = zr;
  p.ybuf = zr;                                           // after zobj dead (P6)
  p.xb   = zr + (size_t)NA * 256;                        // second half
  p.s1  = (u16*)q; q += (size_t)NA * 256 * 2;            // 8.39 MB
  p.agg = (u16*)q; q += (size_t)NA * 256 * 2;            // 8.39 MB
  p.w1t = (u16*)q; q += (size_t)256 * 96 * 2;
  p.wdt = (u16*)q; q += (size_t)NDECP * 256 * 2;
  p.c1t = (u16*)q; q += (size_t)256 * 256 * 2;
  p.wuf = (u16*)q; q += (size_t)256 * 512 * 2;
  p.d1  = (float*)q; q += 256 * 4;
  p.d2  = (float*)q; q += 256 * 4;
  p.bar  = (int*)q; q += 8 * 4;
  p.cur1 = (int*)q; q += (size_t)NA * 4;
  p.cur2 = (int*)q; q += (size_t)NA * 4;
  p.rp1  = (int*)q; q += (size_t)(NA + 1) * 4;
  p.rp2  = (int*)q; q += (size_t)(NA + 1) * 4;
  p.so   = (int*)q; q += (size_t)E1CNT * 4;
  p.ss   = (int*)q;

  // zero bar + cur1 + cur2 in one memset (contiguous)
  hipMemsetAsync(p.bar, 0, (size_t)(8 + 2 * NA) * sizeof(int), stream);

  void* kargs[] = { &p };
  hipError_t err = hipLaunchCooperativeKernel((const void*)mega, dim3(GRID),
                                              dim3(256), kargs, 0, stream);
  if (err != hipSuccess) {
    // fallback: plain launch — co-residency still guaranteed by
    // __launch_bounds__(256,2) resource limits (512 blocks = 2/CU x 256 CU)
    mega<<<dim3(GRID), dim3(256), 0, stream>>>(p);
  }
}